// Round 8
// baseline (83.929 us; speedup 1.0000x reference)
//
#include <hip/hip_runtime.h>

// ScaledDotProductAttention: causal cosine attention.
// B=4 H=16 N=2048 D=64, fp32 in/out, bf16 MFMA compute.
//
// Round 8: QBLK=128 (4 waves), paired q-blocks (15-p, p) -> uniform 34
// K-tile iters/block; 512 blocks = 2 blocks/CU = 4 waves/SIMD (r7 had 2).
// Cycle accounting (r7): MFMA pipe needs ~14 us, VALU ~18.5 us; wall was
// 73 us -> latency-bound at 2 waves/SIMD. Doubling resident waves at
// constant total work should roughly halve the wall.
//  - K,V tiles (KVBLK=64) double-buffered in LDS via global_load_lds(16B),
//    Kn/Vt stored pre-swizzled (elem ^= (row&7)<<3 per 64x64 tile).
//  - no-max softmax: scores cosine-bounded (|s| <= g*log2e ~31.7), so
//    p = exp2(s) directly -- exact by shift-invariance.
//  - swapped-operand MFMA, cvt_pk + permlane32_swap P repack.

#define BATCH 4
#define HEADS 16
#define SEQ   2048
#define DIM   64
#define EPS   1e-8f
#define LOG2E 1.44269504088896340736f

typedef short bf16x8 __attribute__((ext_vector_type(8)));
typedef short s16x4  __attribute__((ext_vector_type(4)));
typedef float fx16   __attribute__((ext_vector_type(16)));
typedef unsigned int u32x4 __attribute__((ext_vector_type(4)));

static __device__ __forceinline__ short f2bf(float x) {
    unsigned u = __float_as_uint(x);
    unsigned r = (u + 0x7fffu + ((u >> 16) & 1u)) >> 16;   // RNE
    return (short)r;
}
static __device__ __forceinline__ unsigned cvt_pk(float lo, float hi) {
    unsigned r;
    asm("v_cvt_pk_bf16_f32 %0, %1, %2" : "=v"(r) : "v"(lo), "v"(hi));
    return r;
}
static __device__ __forceinline__ void gload_lds16(const short* g, short* l) {
    __builtin_amdgcn_global_load_lds(
        (const __attribute__((address_space(1))) void*)g,
        (__attribute__((address_space(3))) void*)l, 16, 0, 0);
}

// ---------------------------------------------------------------------------
// Kernel 1: K rows -> L2-normalized bf16, tiled+swizzled layout:
// Kn[bh][kt][r][e ^ ((r&7)<<3)] = Khat[bh][kt*64+r][e]
// ---------------------------------------------------------------------------
__global__ __launch_bounds__(256) void norm_k(
    const float* __restrict__ K, short* __restrict__ Kn)
{
    const int tid  = threadIdx.x;
    const int lane = tid & 63;
    long long rid = (long long)blockIdx.x * 16 + (tid >> 6) * 4 + (lane >> 4);
    const int c4 = (lane & 15) * 4;

    const float* src = K + rid * DIM;
    float4 v = *(const float4*)(src + c4);
    float ss = v.x * v.x + v.y * v.y + v.z * v.z + v.w * v.w;
    ss += __shfl_xor(ss, 1);
    ss += __shfl_xor(ss, 2);
    ss += __shfl_xor(ss, 4);
    ss += __shfl_xor(ss, 8);
    float s = 1.0f / (sqrtf(ss) + EPS);

    const int bh = (int)(rid >> 11);
    const int n  = (int)(rid & 2047);
    const int kt = n >> 6;
    const int r  = n & 63;
    short* dst = Kn + ((size_t)bh << 17) + (kt << 12) + (r << 6);

    s16x4 o;
    o[0] = f2bf(v.x * s);
    o[1] = f2bf(v.y * s);
    o[2] = f2bf(v.z * s);
    o[3] = f2bf(v.w * s);
    *(s16x4*)(dst + (c4 ^ ((r & 7) << 3))) = o;
}

// ---------------------------------------------------------------------------
// Kernel 2: V [n][d] fp32 -> Vt tiled+swizzled bf16:
// Vt[bh][kt][d][k ^ ((d&7)<<3)] = V[bh][kt*64+k][d]
// ---------------------------------------------------------------------------
#define TLDS 68

__global__ __launch_bounds__(256) void transpose_v(
    const float* __restrict__ V, short* __restrict__ Vt)
{
    const int nt = blockIdx.x;
    const int bh = blockIdx.y;
    const float* Vb = V + ((size_t)bh * SEQ + (size_t)nt * 64) * DIM;
    short* Vo = Vt + ((size_t)bh << 17) + (nt << 12);

    __shared__ short lds[DIM * TLDS];
    const int t  = threadIdx.x;
    const int cg = t & 15;
    const int rr = t >> 4;

#pragma unroll
    for (int i = 0; i < 4; ++i) {
        int n  = rr + i * 16;
        int d0 = cg * 4;
        float4 v = *(const float4*)(Vb + (size_t)n * DIM + d0);
        lds[(d0 + 0) * TLDS + n] = f2bf(v.x);
        lds[(d0 + 1) * TLDS + n] = f2bf(v.y);
        lds[(d0 + 2) * TLDS + n] = f2bf(v.z);
        lds[(d0 + 3) * TLDS + n] = f2bf(v.w);
    }
    __syncthreads();
#pragma unroll
    for (int i = 0; i < 4; ++i) {
        int d  = rr + i * 16;
        int nl = cg * 4;
        s16x4 o;
        o[0] = lds[d * TLDS + nl + 0];
        o[1] = lds[d * TLDS + nl + 1];
        o[2] = lds[d * TLDS + nl + 2];
        o[3] = lds[d * TLDS + nl + 3];
        *(s16x4*)(Vo + (d << 6) + (nl ^ ((d & 7) << 3))) = o;
    }
}

// ---------------------------------------------------------------------------
// Kernel 3: flash attention. 256 threads = 4 waves, QBLK=128, KVBLK=64.
// Block (bh, p) runs TWO sequential q-block phases: qb = 15-p, then qb = p.
// Every block executes exactly 34 K-tile iterations total.
//
// mfma_f32_32x32x16_bf16 layouts:
//   A: row = lane&31, k = (lane>>5)*8 + j
//   B: col = lane&31, k = (lane>>5)*8 + j
//   C/D: col = lane&31, row = (reg&3) + 8*(reg>>2) + 4*(lane>>5)
// ---------------------------------------------------------------------------
__global__ __launch_bounds__(256) void attn_fwd(
    const float* __restrict__ Q, const float* __restrict__ scale,
    const short* __restrict__ Kn, const short* __restrict__ Vt,
    float* __restrict__ out)
{
    const int lid = blockIdx.x;                       // 0..511
    const int bh  = (lid & 7) * 8 + ((lid >> 3) & 7); // XCD lid%8 owns bh/8
    const int p   = lid >> 6;                         // pair index 0..7
    const int tid = threadIdx.x;
    const int w   = tid >> 6;                         // wave 0..3
    const int l   = tid & 63;
    const int lq  = l & 31;
    const int hi  = l >> 5;

    const short* Kb = Kn + ((size_t)bh << 17);
    const short* Vb = Vt + ((size_t)bh << 17);
    const float  g  = scale[bh & (HEADS - 1)];

    __shared__ __align__(16) short ldsK[2][64 * 64];
    __shared__ __align__(16) short ldsV[2][64 * 64];

    const int toff = tid * 8;   // 256 thr x 8 shorts = 2048 shorts per round

#pragma unroll 1
    for (int phase = 0; phase < 2; ++phase) {
        const int qb   = phase == 0 ? (15 - p) : p;   // heavy phase first
        const int wlo  = qb * 128 + w * 32;           // wave's first q-row
        const int whi  = wlo + 31;
        const int qrow = wlo + lq;
        const int nkt  = 2 * qb + 2;

        // all waves done reading LDS from previous phase before restage
        __syncthreads();

        // ---- prologue: stage tile 0 into buffer 0 ----
        gload_lds16(Kb + toff,        &ldsK[0][toff]);
        gload_lds16(Kb + 2048 + toff, &ldsK[0][2048 + toff]);
        gload_lds16(Vb + toff,        &ldsV[0][toff]);
        gload_lds16(Vb + 2048 + toff, &ldsV[0][2048 + toff]);

        // ---- fused Q-norm (overlaps stage-0 latency) ----
        const float* Qrow = Q + ((size_t)bh * SEQ + qrow) * DIM;
        float qv[4][8];
        float ss = 0.f;
#pragma unroll
        for (int c = 0; c < 4; ++c) {
            float4 a = *(const float4*)(Qrow + c * 16 + hi * 8);
            float4 b = *(const float4*)(Qrow + c * 16 + hi * 8 + 4);
            qv[c][0] = a.x; qv[c][1] = a.y; qv[c][2] = a.z; qv[c][3] = a.w;
            qv[c][4] = b.x; qv[c][5] = b.y; qv[c][6] = b.z; qv[c][7] = b.w;
#pragma unroll
            for (int jj = 0; jj < 8; ++jj) ss += qv[c][jj] * qv[c][jj];
        }
        ss += __shfl_xor(ss, 32);
        const float sc = g * LOG2E / (sqrtf(ss) + EPS);

        bf16x8 qbf[4];
#pragma unroll
        for (int c = 0; c < 4; ++c) {
            u32x4 wds;
#pragma unroll
            for (int m = 0; m < 4; ++m)
                wds[m] = cvt_pk(qv[c][2 * m] * sc, qv[c][2 * m + 1] * sc);
            qbf[c] = __builtin_bit_cast(bf16x8, wds);
        }

        fx16 oacc[2];
#pragma unroll
        for (int dt = 0; dt < 2; ++dt)
#pragma unroll
            for (int r = 0; r < 16; ++r) oacc[dt][r] = 0.f;
        float lsum = 0.f;

        int cur = 0;
        for (int kt = 0; kt < nkt; ++kt) {
            __syncthreads();   // drains stage(kt) vmem; prev compute done

            if (kt + 1 < nkt) {   // stage(kt+1) overlaps compute(kt)
                const int nb = cur ^ 1;
                const short* gK = Kb + (size_t)(kt + 1) * 4096;
                const short* gV = Vb + (size_t)(kt + 1) * 4096;
                gload_lds16(gK + toff,        &ldsK[nb][toff]);
                gload_lds16(gK + 2048 + toff, &ldsK[nb][2048 + toff]);
                gload_lds16(gV + toff,        &ldsV[nb][toff]);
                gload_lds16(gV + 2048 + toff, &ldsV[nb][2048 + toff]);
            }

            const int k0 = kt * 64;
            if (k0 <= whi) {   // wave-uniform causal skip (barriers outside)
                const short* lk = ldsK[cur];
                const short* lv = ldsV[cur];

                // ---- K frags from LDS (swizzled), S' = K x Q^T ----
                fx16 sacc[2];
#pragma unroll
                for (int t = 0; t < 2; ++t)
#pragma unroll
                    for (int r = 0; r < 16; ++r) sacc[t][r] = 0.f;

                bf16x8 kf[2][4];
#pragma unroll
                for (int t = 0; t < 2; ++t)
#pragma unroll
                    for (int c = 0; c < 4; ++c) {
                        int r = t * 32 + lq;
                        kf[t][c] = *(const bf16x8*)
                            &lk[(r << 6) + ((c * 16 + hi * 8) ^ ((r & 7) << 3))];
                    }
                __builtin_amdgcn_s_setprio(1);
#pragma unroll
                for (int c = 0; c < 4; ++c) {
                    sacc[0] = __builtin_amdgcn_mfma_f32_32x32x16_bf16(kf[0][c], qbf[c], sacc[0], 0, 0, 0);
                    sacc[1] = __builtin_amdgcn_mfma_f32_32x32x16_bf16(kf[1][c], qbf[c], sacc[1], 0, 0, 0);
                }
                __builtin_amdgcn_s_setprio(0);

                // ---- V frags from LDS (latency hides under softmax) ----
                bf16x8 vf[2][4];
#pragma unroll
                for (int dt = 0; dt < 2; ++dt)
#pragma unroll
                    for (int ks = 0; ks < 4; ++ks) {
                        int d = dt * 32 + lq;
                        vf[dt][ks] = *(const bf16x8*)
                            &lv[(d << 6) + ((ks * 16 + hi * 8) ^ ((d & 7) << 3))];
                    }

                float pv[32];
#pragma unroll
                for (int t = 0; t < 2; ++t)
#pragma unroll
                    for (int r = 0; r < 16; ++r) pv[t * 16 + r] = sacc[t][r];

                // ---- causal mask: only the wave's diagonal tile ----
                if (k0 + 63 > wlo) {
#pragma unroll
                    for (int t = 0; t < 2; ++t)
#pragma unroll
                        for (int r = 0; r < 16; ++r) {
                            int key = k0 + 32 * t + (r & 3) + 8 * (r >> 2) + 4 * hi;
                            if (key > qrow) pv[t * 16 + r] = -3.0e38f;
                        }
                }

                // ---- p = exp2(s) (cosine-bounded, no max shift) ----
#pragma unroll
                for (int r = 0; r < 32; ++r)
                    pv[r] = __builtin_amdgcn_exp2f(pv[r]);

                // ---- lsum += row sum ----
                float ts[16];
#pragma unroll
                for (int r = 0; r < 16; ++r) ts[r] = pv[r] + pv[r + 16];
#pragma unroll
                for (int r = 0; r < 8; ++r) ts[r] += ts[r + 8];
#pragma unroll
                for (int r = 0; r < 4; ++r) ts[r] += ts[r + 4];
                float ps = (ts[0] + ts[1]) + (ts[2] + ts[3]);
                ps += __shfl_xor(ps, 32);
                lsum += ps;

                // ---- repack P -> B-fragments via v_permlane32_swap_b32 ----
                u32x4 paw[4];
#pragma unroll
                for (int ks = 0; ks < 4; ++ks) {
                    const int t = ks >> 1;
                    const int b0 = (ks & 1) * 8;
#pragma unroll
                    for (int m = 0; m < 2; ++m) {
                        unsigned a = cvt_pk(pv[t * 16 + b0 + 2 * m], pv[t * 16 + b0 + 2 * m + 1]);
                        unsigned b = cvt_pk(pv[t * 16 + b0 + 2 * m + 4], pv[t * 16 + b0 + 2 * m + 5]);
                        asm("v_permlane32_swap_b32 %0, %1" : "+v"(a), "+v"(b));
                        paw[ks][m]     = a;
                        paw[ks][m + 2] = b;
                    }
                }

                // ---- O' += Vt x P ----
                __builtin_amdgcn_s_setprio(1);
#pragma unroll
                for (int dt = 0; dt < 2; ++dt)
#pragma unroll
                    for (int ks = 0; ks < 4; ++ks) {
                        bf16x8 pa = __builtin_bit_cast(bf16x8, paw[ks]);
                        oacc[dt] = __builtin_amdgcn_mfma_f32_32x32x16_bf16(vf[dt][ks], pa, oacc[dt], 0, 0, 0);
                    }
                __builtin_amdgcn_s_setprio(0);
            }
            cur ^= 1;
        }

        // ---- phase epilogue: out[q][d] = O'/lsum ----
        float inv = 1.0f / lsum;
        size_t rb = ((size_t)bh * SEQ + (size_t)qrow) * DIM;
#pragma unroll
        for (int dt = 0; dt < 2; ++dt)
#pragma unroll
            for (int g4 = 0; g4 < 4; ++g4) {
                float4 o4;
                o4.x = oacc[dt][4 * g4 + 0] * inv;
                o4.y = oacc[dt][4 * g4 + 1] * inv;
                o4.z = oacc[dt][4 * g4 + 2] * inv;
                o4.w = oacc[dt][4 * g4 + 3] * inv;
                *(float4*)(out + rb + dt * 32 + 8 * g4 + 4 * hi) = o4;
            }
    }
}

// ---------------------------------------------------------------------------
extern "C" void kernel_launch(void* const* d_in, const int* in_sizes, int n_in,
                              void* d_out, int out_size, void* d_ws, size_t ws_size,
                              hipStream_t stream)
{
    const float* Q  = (const float*)d_in[0];
    const float* K  = (const float*)d_in[1];
    const float* V  = (const float*)d_in[2];
    const float* qs = (const float*)d_in[3];
    float* out = (float*)d_out;

    const size_t nElem = (size_t)BATCH * HEADS * SEQ * DIM;
    short* Kn = (short*)d_ws;
    short* Vt = Kn + nElem;

    {
        long long rows = (long long)BATCH * HEADS * SEQ;
        norm_k<<<(int)(rows / 16), 256, 0, stream>>>(K, Kn);
    }
    {
        dim3 grid(SEQ / 64, BATCH * HEADS);
        transpose_v<<<grid, 256, 0, stream>>>(V, Vt);
    }
    {
        // 512 blocks = 2/CU: XCD lid%8 owns bh chunk; 8 q-block pairs per bh
        attn_fwd<<<(SEQ / 128 / 2) * BATCH * HEADS, 256, 0, stream>>>(Q, qs, Kn, Vt, out);
    }
}

// Round 9
// 79.580 us; speedup vs baseline: 1.0546x; 1.0546x over previous
//
#include <hip/hip_runtime.h>

// ScaledDotProductAttention: causal cosine attention.
// B=4 H=16 N=2048 D=64, fp32 in/out, bf16 MFMA compute.
//
// Round 9: r7 structure (QBLK=256, 8 waves, paired q-blocks, 256 blocks)
// + T3/T4: triple-buffered stage, counted vmcnt (never drain to 0 in the
// steady loop), raw s_barriers. Protocol per iteration:
//   barA (readers of overwrite-target done) -> issue stage(kt+2)
//   -> s_waitcnt vmcnt(4) (own stage(kt) landed; newest 4 loads in flight)
//   -> barB (all waves' stage(kt) visible) -> compute(kt).
//  - Kn/Vt pre-swizzled (elem ^= (row&7)<<3 per 64x64 tile), gload_lds(16B).
//  - no-max softmax: scores cosine-bounded (|s| <= g*log2e ~31.7), so
//    p = exp2(s) directly -- exact by shift-invariance.
//  - swapped-operand MFMA, cvt_pk + permlane32_swap P repack.

#define BATCH 4
#define HEADS 16
#define SEQ   2048
#define DIM   64
#define EPS   1e-8f
#define LOG2E 1.44269504088896340736f

typedef short bf16x8 __attribute__((ext_vector_type(8)));
typedef short s16x4  __attribute__((ext_vector_type(4)));
typedef float fx16   __attribute__((ext_vector_type(16)));
typedef unsigned int u32x4 __attribute__((ext_vector_type(4)));

static __device__ __forceinline__ short f2bf(float x) {
    unsigned u = __float_as_uint(x);
    unsigned r = (u + 0x7fffu + ((u >> 16) & 1u)) >> 16;   // RNE
    return (short)r;
}
static __device__ __forceinline__ unsigned cvt_pk(float lo, float hi) {
    unsigned r;
    asm("v_cvt_pk_bf16_f32 %0, %1, %2" : "=v"(r) : "v"(lo), "v"(hi));
    return r;
}
static __device__ __forceinline__ void gload_lds16(const short* g, short* l) {
    __builtin_amdgcn_global_load_lds(
        (const __attribute__((address_space(1))) void*)g,
        (__attribute__((address_space(3))) void*)l, 16, 0, 0);
}

// ---------------------------------------------------------------------------
// Kernel 1: K rows -> L2-normalized bf16, tiled+swizzled layout:
// Kn[bh][kt][r][e ^ ((r&7)<<3)] = Khat[bh][kt*64+r][e]
// ---------------------------------------------------------------------------
__global__ __launch_bounds__(256) void norm_k(
    const float* __restrict__ K, short* __restrict__ Kn)
{
    const int tid  = threadIdx.x;
    const int lane = tid & 63;
    long long rid = (long long)blockIdx.x * 16 + (tid >> 6) * 4 + (lane >> 4);
    const int c4 = (lane & 15) * 4;

    const float* src = K + rid * DIM;
    float4 v = *(const float4*)(src + c4);
    float ss = v.x * v.x + v.y * v.y + v.z * v.z + v.w * v.w;
    ss += __shfl_xor(ss, 1);
    ss += __shfl_xor(ss, 2);
    ss += __shfl_xor(ss, 4);
    ss += __shfl_xor(ss, 8);
    float s = 1.0f / (sqrtf(ss) + EPS);

    const int bh = (int)(rid >> 11);
    const int n  = (int)(rid & 2047);
    const int kt = n >> 6;
    const int r  = n & 63;
    short* dst = Kn + ((size_t)bh << 17) + (kt << 12) + (r << 6);

    s16x4 o;
    o[0] = f2bf(v.x * s);
    o[1] = f2bf(v.y * s);
    o[2] = f2bf(v.z * s);
    o[3] = f2bf(v.w * s);
    *(s16x4*)(dst + (c4 ^ ((r & 7) << 3))) = o;
}

// ---------------------------------------------------------------------------
// Kernel 2: V [n][d] fp32 -> Vt tiled+swizzled bf16:
// Vt[bh][kt][d][k ^ ((d&7)<<3)] = V[bh][kt*64+k][d]
// ---------------------------------------------------------------------------
#define TLDS 68

__global__ __launch_bounds__(256) void transpose_v(
    const float* __restrict__ V, short* __restrict__ Vt)
{
    const int nt = blockIdx.x;
    const int bh = blockIdx.y;
    const float* Vb = V + ((size_t)bh * SEQ + (size_t)nt * 64) * DIM;
    short* Vo = Vt + ((size_t)bh << 17) + (nt << 12);

    __shared__ short lds[DIM * TLDS];
    const int t  = threadIdx.x;
    const int cg = t & 15;
    const int rr = t >> 4;

#pragma unroll
    for (int i = 0; i < 4; ++i) {
        int n  = rr + i * 16;
        int d0 = cg * 4;
        float4 v = *(const float4*)(Vb + (size_t)n * DIM + d0);
        lds[(d0 + 0) * TLDS + n] = f2bf(v.x);
        lds[(d0 + 1) * TLDS + n] = f2bf(v.y);
        lds[(d0 + 2) * TLDS + n] = f2bf(v.z);
        lds[(d0 + 3) * TLDS + n] = f2bf(v.w);
    }
    __syncthreads();
#pragma unroll
    for (int i = 0; i < 4; ++i) {
        int d  = rr + i * 16;
        int nl = cg * 4;
        s16x4 o;
        o[0] = lds[d * TLDS + nl + 0];
        o[1] = lds[d * TLDS + nl + 1];
        o[2] = lds[d * TLDS + nl + 2];
        o[3] = lds[d * TLDS + nl + 3];
        *(s16x4*)(Vo + (d << 6) + (nl ^ ((d & 7) << 3))) = o;
    }
}

// ---------------------------------------------------------------------------
// Kernel 3: flash attention. 512 threads = 8 waves, QBLK=256, KVBLK=64.
// Block (bh, p) runs TWO sequential q-block phases: qb = 7-p, then qb = p.
// Triple-buffered LDS stage, 2 tiles ahead, counted vmcnt.
//
// mfma_f32_32x32x16_bf16 layouts:
//   A: row = lane&31, k = (lane>>5)*8 + j
//   B: col = lane&31, k = (lane>>5)*8 + j
//   C/D: col = lane&31, row = (reg&3) + 8*(reg>>2) + 4*(lane>>5)
// ---------------------------------------------------------------------------
__global__ __launch_bounds__(512) void attn_fwd(
    const float* __restrict__ Q, const float* __restrict__ scale,
    const short* __restrict__ Kn, const short* __restrict__ Vt,
    float* __restrict__ out)
{
    const int lid = blockIdx.x;                       // 0..255
    const int bh  = (lid & 7) * 8 + ((lid >> 3) & 7); // XCD lid%8 owns bh/8
    const int p   = lid >> 6;                         // pair index 0..3
    const int tid = threadIdx.x;
    const int w   = tid >> 6;                         // wave 0..7
    const int l   = tid & 63;
    const int lq  = l & 31;
    const int hi  = l >> 5;

    const short* Kb = Kn + ((size_t)bh << 17);
    const short* Vb = Vt + ((size_t)bh << 17);
    const float  g  = scale[bh & (HEADS - 1)];

    __shared__ __align__(16) short ldsK[3][64 * 64];
    __shared__ __align__(16) short ldsV[3][64 * 64];

    const int toff = tid * 8;   // 512 thr x 8 shorts = full 4096-short tile

#pragma unroll 1
    for (int phase = 0; phase < 2; ++phase) {
        const int qb   = phase == 0 ? (7 - p) : p;    // heavy phase first
        const int wlo  = qb * 256 + w * 32;           // wave's first q-row
        const int whi  = wlo + 31;
        const int qrow = wlo + lq;
        const int nkt  = 4 * qb + 4;

        // phase boundary: all prior reads done, vmcnt fully drained
        __syncthreads();

        // ---- prologue: stage tiles 0 and 1 ----
        gload_lds16(Kb + toff,        &ldsK[0][toff]);
        gload_lds16(Vb + toff,        &ldsV[0][toff]);
        gload_lds16(Kb + 4096 + toff, &ldsK[1][toff]);
        gload_lds16(Vb + 4096 + toff, &ldsV[1][toff]);

        // ---- fused Q-norm (overlaps stage latency; its loads drain vmcnt
        //      once here, before the steady loop) ----
        const float* Qrow = Q + ((size_t)bh * SEQ + qrow) * DIM;
        float qv[4][8];
        float ss = 0.f;
#pragma unroll
        for (int c = 0; c < 4; ++c) {
            float4 a = *(const float4*)(Qrow + c * 16 + hi * 8);
            float4 b = *(const float4*)(Qrow + c * 16 + hi * 8 + 4);
            qv[c][0] = a.x; qv[c][1] = a.y; qv[c][2] = a.z; qv[c][3] = a.w;
            qv[c][4] = b.x; qv[c][5] = b.y; qv[c][6] = b.z; qv[c][7] = b.w;
#pragma unroll
            for (int jj = 0; jj < 8; ++jj) ss += qv[c][jj] * qv[c][jj];
        }
        ss += __shfl_xor(ss, 32);
        const float sc = g * LOG2E / (sqrtf(ss) + EPS);

        bf16x8 qbf[4];
#pragma unroll
        for (int c = 0; c < 4; ++c) {
            u32x4 wds;
#pragma unroll
            for (int m = 0; m < 4; ++m)
                wds[m] = cvt_pk(qv[c][2 * m] * sc, qv[c][2 * m + 1] * sc);
            qbf[c] = __builtin_bit_cast(bf16x8, wds);
        }

        fx16 oacc[2];
#pragma unroll
        for (int dt = 0; dt < 2; ++dt)
#pragma unroll
            for (int r = 0; r < 16; ++r) oacc[dt][r] = 0.f;
        float lsum = 0.f;

        int cur = 0;   // kt % 3
        for (int kt = 0; kt < nkt; ++kt) {
            // bar A: every wave finished compute(kt-1), so the buffer
            // stage(kt+2) will overwrite (== buf[(kt-1)%3]) is free.
            __builtin_amdgcn_s_barrier();

            if (kt + 2 < nkt) {
                int nb = cur + 2; if (nb >= 3) nb -= 3;
                const short* gK = Kb + (size_t)(kt + 2) * 4096;
                const short* gV = Vb + (size_t)(kt + 2) * 4096;
                gload_lds16(gK + toff, &ldsK[nb][toff]);
                gload_lds16(gV + toff, &ldsV[nb][toff]);
                // own stage(kt) done; stages (kt+1),(kt+2) stay in flight
                asm volatile("s_waitcnt vmcnt(4)" ::: "memory");
            } else if (kt + 1 < nkt) {
                asm volatile("s_waitcnt vmcnt(2)" ::: "memory");
            } else {
                asm volatile("s_waitcnt vmcnt(0)" ::: "memory");
            }
            // bar B: all waves' stage(kt) slices visible
            __builtin_amdgcn_s_barrier();

            const int k0 = kt * 64;
            if (k0 <= whi) {   // wave-uniform causal skip (barriers outside)
                const short* lk = ldsK[cur];
                const short* lv = ldsV[cur];

                // ---- K frags from LDS (swizzled), S' = K x Q^T ----
                fx16 sacc[2];
#pragma unroll
                for (int t = 0; t < 2; ++t)
#pragma unroll
                    for (int r = 0; r < 16; ++r) sacc[t][r] = 0.f;

                bf16x8 kf[2][4];
#pragma unroll
                for (int t = 0; t < 2; ++t)
#pragma unroll
                    for (int c = 0; c < 4; ++c) {
                        int r = t * 32 + lq;
                        kf[t][c] = *(const bf16x8*)
                            &lk[(r << 6) + ((c * 16 + hi * 8) ^ ((r & 7) << 3))];
                    }
                __builtin_amdgcn_s_setprio(1);
#pragma unroll
                for (int c = 0; c < 4; ++c) {
                    sacc[0] = __builtin_amdgcn_mfma_f32_32x32x16_bf16(kf[0][c], qbf[c], sacc[0], 0, 0, 0);
                    sacc[1] = __builtin_amdgcn_mfma_f32_32x32x16_bf16(kf[1][c], qbf[c], sacc[1], 0, 0, 0);
                }
                __builtin_amdgcn_s_setprio(0);

                // ---- V frags from LDS (latency hides under softmax) ----
                bf16x8 vf[2][4];
#pragma unroll
                for (int dt = 0; dt < 2; ++dt)
#pragma unroll
                    for (int ks = 0; ks < 4; ++ks) {
                        int d = dt * 32 + lq;
                        vf[dt][ks] = *(const bf16x8*)
                            &lv[(d << 6) + ((ks * 16 + hi * 8) ^ ((d & 7) << 3))];
                    }

                float pv[32];
#pragma unroll
                for (int t = 0; t < 2; ++t)
#pragma unroll
                    for (int r = 0; r < 16; ++r) pv[t * 16 + r] = sacc[t][r];

                // ---- causal mask: only the wave's diagonal tile ----
                if (k0 + 63 > wlo) {
#pragma unroll
                    for (int t = 0; t < 2; ++t)
#pragma unroll
                        for (int r = 0; r < 16; ++r) {
                            int key = k0 + 32 * t + (r & 3) + 8 * (r >> 2) + 4 * hi;
                            if (key > qrow) pv[t * 16 + r] = -3.0e38f;
                        }
                }

                // ---- p = exp2(s) (cosine-bounded, no max shift) ----
#pragma unroll
                for (int r = 0; r < 32; ++r)
                    pv[r] = __builtin_amdgcn_exp2f(pv[r]);

                // ---- lsum += row sum ----
                float ts[16];
#pragma unroll
                for (int r = 0; r < 16; ++r) ts[r] = pv[r] + pv[r + 16];
#pragma unroll
                for (int r = 0; r < 8; ++r) ts[r] += ts[r + 8];
#pragma unroll
                for (int r = 0; r < 4; ++r) ts[r] += ts[r + 4];
                float ps = (ts[0] + ts[1]) + (ts[2] + ts[3]);
                ps += __shfl_xor(ps, 32);
                lsum += ps;

                // ---- repack P -> B-fragments via v_permlane32_swap_b32 ----
                u32x4 paw[4];
#pragma unroll
                for (int ks = 0; ks < 4; ++ks) {
                    const int t = ks >> 1;
                    const int b0 = (ks & 1) * 8;
#pragma unroll
                    for (int m = 0; m < 2; ++m) {
                        unsigned a = cvt_pk(pv[t * 16 + b0 + 2 * m], pv[t * 16 + b0 + 2 * m + 1]);
                        unsigned b = cvt_pk(pv[t * 16 + b0 + 2 * m + 4], pv[t * 16 + b0 + 2 * m + 5]);
                        asm("v_permlane32_swap_b32 %0, %1" : "+v"(a), "+v"(b));
                        paw[ks][m]     = a;
                        paw[ks][m + 2] = b;
                    }
                }

                // ---- O' += Vt x P ----
                __builtin_amdgcn_s_setprio(1);
#pragma unroll
                for (int dt = 0; dt < 2; ++dt)
#pragma unroll
                    for (int ks = 0; ks < 4; ++ks) {
                        bf16x8 pa = __builtin_bit_cast(bf16x8, paw[ks]);
                        oacc[dt] = __builtin_amdgcn_mfma_f32_32x32x16_bf16(vf[dt][ks], pa, oacc[dt], 0, 0, 0);
                    }
                __builtin_amdgcn_s_setprio(0);
            }
            cur = (cur == 2) ? 0 : cur + 1;
        }

        // ---- phase epilogue: out[q][d] = O'/lsum ----
        float inv = 1.0f / lsum;
        size_t rb = ((size_t)bh * SEQ + (size_t)qrow) * DIM;
#pragma unroll
        for (int dt = 0; dt < 2; ++dt)
#pragma unroll
            for (int g4 = 0; g4 < 4; ++g4) {
                float4 o4;
                o4.x = oacc[dt][4 * g4 + 0] * inv;
                o4.y = oacc[dt][4 * g4 + 1] * inv;
                o4.z = oacc[dt][4 * g4 + 2] * inv;
                o4.w = oacc[dt][4 * g4 + 3] * inv;
                *(float4*)(out + rb + dt * 32 + 8 * g4 + 4 * hi) = o4;
            }
    }
}

// ---------------------------------------------------------------------------
extern "C" void kernel_launch(void* const* d_in, const int* in_sizes, int n_in,
                              void* d_out, int out_size, void* d_ws, size_t ws_size,
                              hipStream_t stream)
{
    const float* Q  = (const float*)d_in[0];
    const float* K  = (const float*)d_in[1];
    const float* V  = (const float*)d_in[2];
    const float* qs = (const float*)d_in[3];
    float* out = (float*)d_out;

    const size_t nElem = (size_t)BATCH * HEADS * SEQ * DIM;
    short* Kn = (short*)d_ws;
    short* Vt = Kn + nElem;

    {
        long long rows = (long long)BATCH * HEADS * SEQ;
        norm_k<<<(int)(rows / 16), 256, 0, stream>>>(K, Kn);
    }
    {
        dim3 grid(SEQ / 64, BATCH * HEADS);
        transpose_v<<<grid, 256, 0, stream>>>(V, Vt);
    }
    {
        // 256 blocks = 1/CU: XCD lid%8 owns bh chunk; 4 q-block pairs per bh
        attn_fwd<<<(SEQ / 256 / 2) * BATCH * HEADS, 512, 0, stream>>>(Q, qs, Kn, Vt, out);
    }
}

// Round 10
// 73.897 us; speedup vs baseline: 1.1358x; 1.0769x over previous
//
#include <hip/hip_runtime.h>

// ScaledDotProductAttention: causal cosine attention.
// B=4 H=16 N=2048 D=64, fp32 in/out, bf16 MFMA compute.
//
// Round 10: r9 inner loop, but grid 512 (one q-block per block, no pairing)
// -> 2 blocks/CU co-resident = 4 waves/SIMD (r7/r9 had 2). Two independent
// barrier groups per CU fill each other's latency stalls; heavy-first
// dispatch + backfill bounds the imbalance. Staging total unchanged (147 MB).
//  - QBLK=256 (8 waves x 32 q-rows), KVBLK=64, triple-buffered LDS stage,
//    counted vmcnt (4/2/0), raw s_barriers.
//  - Kn/Vt pre-swizzled (elem ^= (row&7)<<3 per 64x64 tile), gload_lds(16B).
//  - no-max softmax: scores cosine-bounded (|s| <= g*log2e ~31.7), so
//    p = exp2(s) directly -- exact by shift-invariance.
//  - swapped-operand MFMA, cvt_pk + permlane32_swap P repack.

#define BATCH 4
#define HEADS 16
#define SEQ   2048
#define DIM   64
#define EPS   1e-8f
#define LOG2E 1.44269504088896340736f

typedef short bf16x8 __attribute__((ext_vector_type(8)));
typedef short s16x4  __attribute__((ext_vector_type(4)));
typedef float fx16   __attribute__((ext_vector_type(16)));
typedef unsigned int u32x4 __attribute__((ext_vector_type(4)));

static __device__ __forceinline__ short f2bf(float x) {
    unsigned u = __float_as_uint(x);
    unsigned r = (u + 0x7fffu + ((u >> 16) & 1u)) >> 16;   // RNE
    return (short)r;
}
static __device__ __forceinline__ unsigned cvt_pk(float lo, float hi) {
    unsigned r;
    asm("v_cvt_pk_bf16_f32 %0, %1, %2" : "=v"(r) : "v"(lo), "v"(hi));
    return r;
}
static __device__ __forceinline__ void gload_lds16(const short* g, short* l) {
    __builtin_amdgcn_global_load_lds(
        (const __attribute__((address_space(1))) void*)g,
        (__attribute__((address_space(3))) void*)l, 16, 0, 0);
}

// ---------------------------------------------------------------------------
// Kernel 1: K rows -> L2-normalized bf16, tiled+swizzled layout:
// Kn[bh][kt][r][e ^ ((r&7)<<3)] = Khat[bh][kt*64+r][e]
// ---------------------------------------------------------------------------
__global__ __launch_bounds__(256) void norm_k(
    const float* __restrict__ K, short* __restrict__ Kn)
{
    const int tid  = threadIdx.x;
    const int lane = tid & 63;
    long long rid = (long long)blockIdx.x * 16 + (tid >> 6) * 4 + (lane >> 4);
    const int c4 = (lane & 15) * 4;

    const float* src = K + rid * DIM;
    float4 v = *(const float4*)(src + c4);
    float ss = v.x * v.x + v.y * v.y + v.z * v.z + v.w * v.w;
    ss += __shfl_xor(ss, 1);
    ss += __shfl_xor(ss, 2);
    ss += __shfl_xor(ss, 4);
    ss += __shfl_xor(ss, 8);
    float s = 1.0f / (sqrtf(ss) + EPS);

    const int bh = (int)(rid >> 11);
    const int n  = (int)(rid & 2047);
    const int kt = n >> 6;
    const int r  = n & 63;
    short* dst = Kn + ((size_t)bh << 17) + (kt << 12) + (r << 6);

    s16x4 o;
    o[0] = f2bf(v.x * s);
    o[1] = f2bf(v.y * s);
    o[2] = f2bf(v.z * s);
    o[3] = f2bf(v.w * s);
    *(s16x4*)(dst + (c4 ^ ((r & 7) << 3))) = o;
}

// ---------------------------------------------------------------------------
// Kernel 2: V [n][d] fp32 -> Vt tiled+swizzled bf16:
// Vt[bh][kt][d][k ^ ((d&7)<<3)] = V[bh][kt*64+k][d]
// ---------------------------------------------------------------------------
#define TLDS 68

__global__ __launch_bounds__(256) void transpose_v(
    const float* __restrict__ V, short* __restrict__ Vt)
{
    const int nt = blockIdx.x;
    const int bh = blockIdx.y;
    const float* Vb = V + ((size_t)bh * SEQ + (size_t)nt * 64) * DIM;
    short* Vo = Vt + ((size_t)bh << 17) + (nt << 12);

    __shared__ short lds[DIM * TLDS];
    const int t  = threadIdx.x;
    const int cg = t & 15;
    const int rr = t >> 4;

#pragma unroll
    for (int i = 0; i < 4; ++i) {
        int n  = rr + i * 16;
        int d0 = cg * 4;
        float4 v = *(const float4*)(Vb + (size_t)n * DIM + d0);
        lds[(d0 + 0) * TLDS + n] = f2bf(v.x);
        lds[(d0 + 1) * TLDS + n] = f2bf(v.y);
        lds[(d0 + 2) * TLDS + n] = f2bf(v.z);
        lds[(d0 + 3) * TLDS + n] = f2bf(v.w);
    }
    __syncthreads();
#pragma unroll
    for (int i = 0; i < 4; ++i) {
        int d  = rr + i * 16;
        int nl = cg * 4;
        s16x4 o;
        o[0] = lds[d * TLDS + nl + 0];
        o[1] = lds[d * TLDS + nl + 1];
        o[2] = lds[d * TLDS + nl + 2];
        o[3] = lds[d * TLDS + nl + 3];
        *(s16x4*)(Vo + (d << 6) + (nl ^ ((d & 7) << 3))) = o;
    }
}

// ---------------------------------------------------------------------------
// Kernel 3: flash attention. 512 threads = 8 waves, QBLK=256, KVBLK=64.
// One q-block per block; grid 512 = 2 blocks/CU. Triple-buffered stage,
// 2 tiles ahead, counted vmcnt (4/2/0), raw s_barriers.
//
// mfma_f32_32x32x16_bf16 layouts:
//   A: row = lane&31, k = (lane>>5)*8 + j
//   B: col = lane&31, k = (lane>>5)*8 + j
//   C/D: col = lane&31, row = (reg&3) + 8*(reg>>2) + 4*(lane>>5)
// ---------------------------------------------------------------------------
__global__ __launch_bounds__(512) void attn_fwd(
    const float* __restrict__ Q, const float* __restrict__ scale,
    const short* __restrict__ Kn, const short* __restrict__ Vt,
    float* __restrict__ out)
{
    const int lid = blockIdx.x;                       // 0..511
    const int bh  = (lid & 7) * 8 + ((lid >> 3) & 7); // XCD lid%8 owns bh/8
    const int qb  = 7 - (lid >> 6);                   // heavy q-blocks first
    const int tid = threadIdx.x;
    const int w   = tid >> 6;                         // wave 0..7
    const int l   = tid & 63;
    const int lq  = l & 31;
    const int hi  = l >> 5;

    const short* Kb = Kn + ((size_t)bh << 17);
    const short* Vb = Vt + ((size_t)bh << 17);
    const float  g  = scale[bh & (HEADS - 1)];

    __shared__ __align__(16) short ldsK[3][64 * 64];
    __shared__ __align__(16) short ldsV[3][64 * 64];

    const int toff = tid * 8;   // 512 thr x 8 shorts = full 4096-short tile

    const int wlo  = qb * 256 + w * 32;   // wave's first q-row
    const int whi  = wlo + 31;
    const int qrow = wlo + lq;
    const int nkt  = 4 * qb + 4;

    // ---- prologue: stage tiles 0 and 1 ----
    gload_lds16(Kb + toff,        &ldsK[0][toff]);
    gload_lds16(Vb + toff,        &ldsV[0][toff]);
    gload_lds16(Kb + 4096 + toff, &ldsK[1][toff]);
    gload_lds16(Vb + 4096 + toff, &ldsV[1][toff]);

    // ---- fused Q-norm (overlaps stage latency; its own loads drain vmcnt
    //      once here, before the steady loop) ----
    const float* Qrow = Q + ((size_t)bh * SEQ + qrow) * DIM;
    float qv[4][8];
    float ss = 0.f;
#pragma unroll
    for (int c = 0; c < 4; ++c) {
        float4 a = *(const float4*)(Qrow + c * 16 + hi * 8);
        float4 b = *(const float4*)(Qrow + c * 16 + hi * 8 + 4);
        qv[c][0] = a.x; qv[c][1] = a.y; qv[c][2] = a.z; qv[c][3] = a.w;
        qv[c][4] = b.x; qv[c][5] = b.y; qv[c][6] = b.z; qv[c][7] = b.w;
#pragma unroll
        for (int jj = 0; jj < 8; ++jj) ss += qv[c][jj] * qv[c][jj];
    }
    ss += __shfl_xor(ss, 32);
    const float sc = g * LOG2E / (sqrtf(ss) + EPS);

    bf16x8 qbf[4];
#pragma unroll
    for (int c = 0; c < 4; ++c) {
        u32x4 wds;
#pragma unroll
        for (int m = 0; m < 4; ++m)
            wds[m] = cvt_pk(qv[c][2 * m] * sc, qv[c][2 * m + 1] * sc);
        qbf[c] = __builtin_bit_cast(bf16x8, wds);
    }

    fx16 oacc[2];
#pragma unroll
    for (int dt = 0; dt < 2; ++dt)
#pragma unroll
        for (int r = 0; r < 16; ++r) oacc[dt][r] = 0.f;
    float lsum = 0.f;

    int cur = 0;   // kt % 3
    for (int kt = 0; kt < nkt; ++kt) {
        // bar A: every wave finished compute(kt-1), so the buffer
        // stage(kt+2) will overwrite (== buf[(kt-1)%3]) is free.
        __builtin_amdgcn_s_barrier();

        if (kt + 2 < nkt) {
            int nb = cur + 2; if (nb >= 3) nb -= 3;
            const short* gK = Kb + (size_t)(kt + 2) * 4096;
            const short* gV = Vb + (size_t)(kt + 2) * 4096;
            gload_lds16(gK + toff, &ldsK[nb][toff]);
            gload_lds16(gV + toff, &ldsV[nb][toff]);
            // own stage(kt) done; stages (kt+1),(kt+2) stay in flight
            asm volatile("s_waitcnt vmcnt(4)" ::: "memory");
        } else if (kt + 1 < nkt) {
            asm volatile("s_waitcnt vmcnt(2)" ::: "memory");
        } else {
            asm volatile("s_waitcnt vmcnt(0)" ::: "memory");
        }
        // bar B: all waves' stage(kt) slices visible
        __builtin_amdgcn_s_barrier();

        const int k0 = kt * 64;
        if (k0 <= whi) {   // wave-uniform causal skip (barriers outside)
            const short* lk = ldsK[cur];
            const short* lv = ldsV[cur];

            // ---- K frags from LDS (swizzled), S' = K x Q^T ----
            fx16 sacc[2];
#pragma unroll
            for (int t = 0; t < 2; ++t)
#pragma unroll
                for (int r = 0; r < 16; ++r) sacc[t][r] = 0.f;

            bf16x8 kf[2][4];
#pragma unroll
            for (int t = 0; t < 2; ++t)
#pragma unroll
                for (int c = 0; c < 4; ++c) {
                    int r = t * 32 + lq;
                    kf[t][c] = *(const bf16x8*)
                        &lk[(r << 6) + ((c * 16 + hi * 8) ^ ((r & 7) << 3))];
                }
            __builtin_amdgcn_s_setprio(1);
#pragma unroll
            for (int c = 0; c < 4; ++c) {
                sacc[0] = __builtin_amdgcn_mfma_f32_32x32x16_bf16(kf[0][c], qbf[c], sacc[0], 0, 0, 0);
                sacc[1] = __builtin_amdgcn_mfma_f32_32x32x16_bf16(kf[1][c], qbf[c], sacc[1], 0, 0, 0);
            }
            __builtin_amdgcn_s_setprio(0);

            // ---- V frags from LDS (latency hides under softmax) ----
            bf16x8 vf[2][4];
#pragma unroll
            for (int dt = 0; dt < 2; ++dt)
#pragma unroll
                for (int ks = 0; ks < 4; ++ks) {
                    int d = dt * 32 + lq;
                    vf[dt][ks] = *(const bf16x8*)
                        &lv[(d << 6) + ((ks * 16 + hi * 8) ^ ((d & 7) << 3))];
                }

            float pv[32];
#pragma unroll
            for (int t = 0; t < 2; ++t)
#pragma unroll
                for (int r = 0; r < 16; ++r) pv[t * 16 + r] = sacc[t][r];

            // ---- causal mask: only the wave's diagonal tile ----
            if (k0 + 63 > wlo) {
#pragma unroll
                for (int t = 0; t < 2; ++t)
#pragma unroll
                    for (int r = 0; r < 16; ++r) {
                        int key = k0 + 32 * t + (r & 3) + 8 * (r >> 2) + 4 * hi;
                        if (key > qrow) pv[t * 16 + r] = -3.0e38f;
                    }
            }

            // ---- p = exp2(s) (cosine-bounded, no max shift) ----
#pragma unroll
            for (int r = 0; r < 32; ++r)
                pv[r] = __builtin_amdgcn_exp2f(pv[r]);

            // ---- lsum += row sum ----
            float ts[16];
#pragma unroll
            for (int r = 0; r < 16; ++r) ts[r] = pv[r] + pv[r + 16];
#pragma unroll
            for (int r = 0; r < 8; ++r) ts[r] += ts[r + 8];
#pragma unroll
            for (int r = 0; r < 4; ++r) ts[r] += ts[r + 4];
            float ps = (ts[0] + ts[1]) + (ts[2] + ts[3]);
            ps += __shfl_xor(ps, 32);
            lsum += ps;

            // ---- repack P -> B-fragments via v_permlane32_swap_b32 ----
            u32x4 paw[4];
#pragma unroll
            for (int ks = 0; ks < 4; ++ks) {
                const int t = ks >> 1;
                const int b0 = (ks & 1) * 8;
#pragma unroll
                for (int m = 0; m < 2; ++m) {
                    unsigned a = cvt_pk(pv[t * 16 + b0 + 2 * m], pv[t * 16 + b0 + 2 * m + 1]);
                    unsigned b = cvt_pk(pv[t * 16 + b0 + 2 * m + 4], pv[t * 16 + b0 + 2 * m + 5]);
                    asm("v_permlane32_swap_b32 %0, %1" : "+v"(a), "+v"(b));
                    paw[ks][m]     = a;
                    paw[ks][m + 2] = b;
                }
            }

            // ---- O' += Vt x P ----
            __builtin_amdgcn_s_setprio(1);
#pragma unroll
            for (int dt = 0; dt < 2; ++dt)
#pragma unroll
                for (int ks = 0; ks < 4; ++ks) {
                    bf16x8 pa = __builtin_bit_cast(bf16x8, paw[ks]);
                    oacc[dt] = __builtin_amdgcn_mfma_f32_32x32x16_bf16(vf[dt][ks], pa, oacc[dt], 0, 0, 0);
                }
            __builtin_amdgcn_s_setprio(0);
        }
        cur = (cur == 2) ? 0 : cur + 1;
    }

    // ---- epilogue: out[q][d] = O'/lsum ----
    float inv = 1.0f / lsum;
    size_t rb = ((size_t)bh * SEQ + (size_t)qrow) * DIM;
#pragma unroll
    for (int dt = 0; dt < 2; ++dt)
#pragma unroll
        for (int g4 = 0; g4 < 4; ++g4) {
            float4 o4;
            o4.x = oacc[dt][4 * g4 + 0] * inv;
            o4.y = oacc[dt][4 * g4 + 1] * inv;
            o4.z = oacc[dt][4 * g4 + 2] * inv;
            o4.w = oacc[dt][4 * g4 + 3] * inv;
            *(float4*)(out + rb + dt * 32 + 8 * g4 + 4 * hi) = o4;
        }
}

// ---------------------------------------------------------------------------
extern "C" void kernel_launch(void* const* d_in, const int* in_sizes, int n_in,
                              void* d_out, int out_size, void* d_ws, size_t ws_size,
                              hipStream_t stream)
{
    const float* Q  = (const float*)d_in[0];
    const float* K  = (const float*)d_in[1];
    const float* V  = (const float*)d_in[2];
    const float* qs = (const float*)d_in[3];
    float* out = (float*)d_out;

    const size_t nElem = (size_t)BATCH * HEADS * SEQ * DIM;
    short* Kn = (short*)d_ws;
    short* Vt = Kn + nElem;

    {
        long long rows = (long long)BATCH * HEADS * SEQ;
        norm_k<<<(int)(rows / 16), 256, 0, stream>>>(K, Kn);
    }
    {
        dim3 grid(SEQ / 64, BATCH * HEADS);
        transpose_v<<<grid, 256, 0, stream>>>(V, Vt);
    }
    {
        // 512 blocks = 2/CU: XCD lid%8 owns bh chunk; 8 q-blocks per bh
        attn_fwd<<<(SEQ / 256) * BATCH * HEADS, 512, 0, stream>>>(Q, qs, Kn, Vt, out);
    }
}